// Round 7
// baseline (279.671 us; speedup 1.0000x reference)
//
#include <hip/hip_runtime.h>
#include <hip/hip_bf16.h>

// Problem constants (from reference)
#define BB    16
#define LQ    64
#define LD    2048
#define HH    1024
#define DIM   128
#define MAXK  513          // LD/PF + 1 with PF=4
#define SCH   9            // ceil(513/64) cluster chunks for simmax
#define DGRID 1024         // d-encode blocks (32768 / 32)
#define QGRID 32           // q-encode blocks (1024 / 32)

typedef __attribute__((ext_vector_type(8))) short short8;
typedef __attribute__((ext_vector_type(4))) float f32x4;

// s_waitcnt imms: vmcnt(N) with expcnt/lgkmcnt no-wait.
// gfx9 layout: vmcnt[3:0](+[15:14]), expcnt[6:4], lgkmcnt[11:8].
// 0x0F70 keeps bits 12/13 clear (safe whether lgkmcnt is 4- or 6-bit).
#define WC_VM6 0x0F76
#define WC_VM0 0x0F70

__device__ __forceinline__ float b2f(ushort u) {
    union { float f; unsigned int u32; } c; c.u32 = ((unsigned int)u) << 16; return c.f;
}
__device__ __forceinline__ ushort f2b_rn(float f) {
    unsigned int x = __float_as_uint(f);
    return (ushort)((x + 0x7fffu + ((x >> 16) & 1u)) >> 16);
}

// async global->LDS, 16B/lane; LDS dest = wave-uniform base + lane*16
__device__ __forceinline__ void gld16(void* lds, const void* g) {
    __builtin_amdgcn_global_load_lds(
        (const __attribute__((address_space(1))) unsigned int*)g,
        (__attribute__((address_space(3))) unsigned int*)lds,
        16, 0, 0);
}

// ---------------------------------------------------------------------------
// Fused prep: blocks 0..511 transpose+round W -> Wt bf16; 512..527 kvals.
__global__ __launch_bounds__(256) void prep_kb_kernel(
    const float* __restrict__ W,
    const int*   __restrict__ d_mask,
    const int*   __restrict__ pf,
    ushort*      __restrict__ Wt,
    int*         __restrict__ kvals)
{
    __shared__ int red[4];
    int bid = blockIdx.x, t = threadIdx.x;
    if (bid < 512) {
        int idx = bid * 256 + t;     // < H*DIM = 131072
        int h = idx >> 7;            // row in H
        int n = idx & 127;           // col in DIM
        Wt[n * HH + h] = f2b_rn(W[idx]);
    } else {
        int b = bid - 512;
        int lane = t & 63, wave = t >> 6;
        int s = 0;
        for (int i = t; i < LD; i += 256) s += (d_mask[b * LD + i] > 0) ? 1 : 0;
        #pragma unroll
        for (int m = 1; m < 64; m <<= 1) s += __shfl_xor(s, m);
        if (lane == 0) red[wave] = s;
        __syncthreads();
        if (t == 0) {
            int v = red[0] + red[1] + red[2] + red[3];
            if (v < 2) v = 2;
            int pfv = pf[0];
            if (pfv < 1 || pfv > LD) pfv = 4;   // defensive
            kvals[b] = v / pfv + 1;
        }
    }
}

// ---------------------------------------------------------------------------
// Encode + fused pooled-scatter, BARRIER-FREE pipelined K-loop.
// Block = 256 thr = 4 waves. Wave w: rows rg=w&1 (16), cols cg=w>>1 (64).
// Each wave owns a private 2-slot LDS ring (slot = A 2KB + B 4KB = 384 u16B
// units); fills it ONLY with its own gld16, waits with fine-grained
// s_waitcnt vmcnt(6) (next chunk's 6 loads stay in flight) - no __syncthreads
// in the loop. 2 MFMA passes: A split hi+lo (exact), W rounded bf16.
// XOR-swizzled 16B units: A key=row&7 (128B rows), B key=(row>>1)&3 (64B rows)
// -> all ds_read_b128 are 2-way (free).
__global__ __launch_bounds__(256, 3) void encode_kernel(
    const float*  __restrict__ Xd,      // [32768][H]
    const float*  __restrict__ Xq,      // [1024][H]
    const ushort* __restrict__ Wt,      // [DIM][H] bf16 rounded
    const float*  __restrict__ bias,    // [DIM]
    const int*    __restrict__ mask_d,  // [32768]
    const int*    __restrict__ mask_q,  // [1024]
    const int*    __restrict__ labels,  // [32768]
    const int*    __restrict__ kvals,   // [BB]
    float*        __restrict__ sums,    // [BB][MAXK][DIM]
    float*        __restrict__ q_repr)  // [1024][DIM]
{
    __shared__ __align__(16) uint4 buf[4 * 768];   // 4 waves x 2 slots x 384 = 48 KB
    __shared__ float ssh[32][2];

    const int bid = blockIdx.x;
    const bool isq = bid >= DGRID;
    const float* X = isq ? Xq : Xd;
    const long row0 = isq ? (long)(bid - DGRID) * 32 : (long)bid * 32;

    const int t = threadIdx.x;
    const int w = t >> 6, lane = t & 63;
    const int m16 = lane & 15, quad = lane >> 4;
    const int rg = w & 1, cg = w >> 1;
    const int wbase = w * 768;

    // staging sources (per lane); advance by 32 elements per chunk
    const float*  gA0 = X + (row0 + rg * 16 + (lane >> 3)) * HH
                          + (((lane & 7) ^ ((lane >> 3) & 7)) * 4);
    const float*  gA1 = gA0 + 8 * HH;
    const ushort* gB0 = Wt + (long)(cg * 64 + (lane >> 2)) * HH
                           + (((lane & 3) ^ ((lane >> 3) & 3)) * 8);
    const ushort* gB1 = gB0 + 16 * HH;
    const ushort* gB2 = gB0 + 32 * HH;
    const ushort* gB3 = gB0 + 48 * HH;

    auto stage = [&](int slot, int chunk) {
        const int ko = chunk * 32;
        uint4* s = &buf[wbase + slot * 384];
        gld16(s +   0, gA0 + ko);
        gld16(s +  64, gA1 + ko);
        gld16(s + 128, gB0 + ko);
        gld16(s + 192, gB1 + ko);
        gld16(s + 256, gB2 + ko);
        gld16(s + 320, gB3 + ko);
    };

    f32x4 acc[4];
    #pragma unroll
    for (int j = 0; j < 4; ++j) acc[j] = (f32x4){0.f, 0.f, 0.f, 0.f};

    stage(0, 0);
    stage(1, 1);

    const int sw = m16 & 7;
    const int bk = (m16 >> 1) & 3;

    #pragma unroll 4
    for (int c = 0; c < 32; ++c) {
        __builtin_amdgcn_sched_barrier(0);
        if (c < 31) __builtin_amdgcn_s_waitcnt(WC_VM6);   // chunk c staged; c+1 in flight
        else        __builtin_amdgcn_s_waitcnt(WC_VM0);   // last chunk: drain
        __builtin_amdgcn_sched_barrier(0);

        const uint4* sl = &buf[wbase + (c & 1) * 384];

        float4 va0 = *(const float4*)&sl[m16 * 8 + ((2 * quad)     ^ sw)];
        float4 va1 = *(const float4*)&sl[m16 * 8 + ((2 * quad + 1) ^ sw)];
        float av[8];
        *(float4*)(av) = va0; *(float4*)(av + 4) = va1;
        short8 ah, al;
        #pragma unroll
        for (int j = 0; j < 8; ++j) {
            unsigned int ux = __float_as_uint(av[j]);
            ah[j] = (short)(ux >> 16);
            float hif = __uint_as_float(ux & 0xffff0000u);
            al[j] = (short)(__float_as_uint(av[j] - hif) >> 16);
        }

        #pragma unroll
        for (int ct = 0; ct < 4; ++ct) {
            short8 bf = *(const short8*)&sl[128 + (ct * 16 + m16) * 4 + (quad ^ bk)];
            acc[ct] = __builtin_amdgcn_mfma_f32_16x16x32_bf16(ah, bf, acc[ct], 0, 0, 0);
            acc[ct] = __builtin_amdgcn_mfma_f32_16x16x32_bf16(al, bf, acc[ct], 0, 0, 0);
        }

        __builtin_amdgcn_sched_barrier(0);
        if (c < 30) stage(c & 1, c + 2);   // reissue into the slot just consumed
    }

    // epilogue: bias, cross-wave row norm (col halves), mask, scatter/store
    float bia[4];
    #pragma unroll
    for (int ct = 0; ct < 4; ++ct) bia[ct] = bias[cg * 64 + ct * 16 + m16];

    float vv[4][4];
    float ssp[4] = {0.f, 0.f, 0.f, 0.f};
    #pragma unroll
    for (int ct = 0; ct < 4; ++ct)
        #pragma unroll
        for (int r = 0; r < 4; ++r) {
            vv[ct][r] = acc[ct][r] + bia[ct];
            ssp[r] += vv[ct][r] * vv[ct][r];
        }
    #pragma unroll
    for (int r = 0; r < 4; ++r) {
        ssp[r] += __shfl_xor(ssp[r], 1);
        ssp[r] += __shfl_xor(ssp[r], 2);
        ssp[r] += __shfl_xor(ssp[r], 4);
        ssp[r] += __shfl_xor(ssp[r], 8);
    }
    if (m16 == 0) {
        #pragma unroll
        for (int r = 0; r < 4; ++r) ssh[rg * 16 + quad * 4 + r][cg] = ssp[r];
    }
    __syncthreads();

    #pragma unroll
    for (int r = 0; r < 4; ++r) {
        int rowl = rg * 16 + quad * 4 + r;
        long rowg = row0 + rowl;
        float ss = ssh[rowl][0] + ssh[rowl][1];
        float scale = 1.0f / fmaxf(sqrtf(ss), 1e-12f);
        if (isq) {
            scale *= (float)mask_q[rowg];
            #pragma unroll
            for (int ct = 0; ct < 4; ++ct)
                q_repr[rowg * DIM + cg * 64 + ct * 16 + m16] = vv[ct][r] * scale;
        } else if (mask_d[rowg] > 0) {
            int b = (int)(rowg >> 11);
            int seg = labels[rowg] % kvals[b];
            float* sp = sums + ((long)b * MAXK + seg) * DIM + cg * 64 + m16;
            #pragma unroll
            for (int ct = 0; ct < 4; ++ct)
                atomicAdd(sp + ct * 16, vv[ct][r] * scale);
        }
    }
}

// ---------------------------------------------------------------------------
// Sim via MFMA: block = (b, 64-cluster chunk). Stage Q (split bf16) and C
// (rounded bf16) in LDS, 16x16x32 MFMA over K=DIM=128, normalize(sum) trick
// via per-cluster rsqrt, shuffle-max over clusters -> pmax[b][chunk][64].
__global__ __launch_bounds__(256) void simmax_kernel(
    const float* __restrict__ q_repr,   // [B][LQ][DIM]
    const float* __restrict__ sums,     // [B][MAXK][DIM] raw cluster sums
    const int*   __restrict__ kvals,
    float*       __restrict__ pmax)     // [B][SCH][64]
{
    __shared__ __align__(16) ushort Qh[64 * 136];
    __shared__ __align__(16) ushort Ql[64 * 136];
    __shared__ __align__(16) ushort Ch[64 * 136];
    __shared__ float cn[64];

    int b = blockIdx.x / SCH, chunk = blockIdx.x % SCH;
    int t = threadIdx.x, w = t >> 6, lane = t & 63;
    int m16 = lane & 15, quad = lane >> 4;

    // stage Q (64 rows x 128), split hi/lo
    #pragma unroll
    for (int i = 0; i < 8; ++i) {
        int flat = i * 256 + t;          // float4 index
        int row = flat >> 5, c4 = flat & 31;
        float4 v = *(const float4*)(q_repr + ((long)b * LQ + row) * DIM + c4 * 4);
        float x[4]; *(float4*)x = v;
        ushort4 h, l;
        ushort* hp = (ushort*)&h; ushort* lp = (ushort*)&l;
        #pragma unroll
        for (int j = 0; j < 4; ++j) {
            unsigned int ux = __float_as_uint(x[j]);
            hp[j] = (ushort)(ux >> 16);
            lp[j] = f2b_rn(x[j] - __uint_as_float(ux & 0xffff0000u));
        }
        *(ushort4*)&Qh[row * 136 + c4 * 4] = h;
        *(ushort4*)&Ql[row * 136 + c4 * 4] = l;
    }
    // stage C (64 clusters x 128), rounded bf16
    #pragma unroll
    for (int i = 0; i < 8; ++i) {
        int flat = i * 256 + t;
        int row = flat >> 5, c4 = flat & 31;
        int kk = chunk * 64 + row;
        float4 v = (kk < MAXK)
            ? *(const float4*)(sums + ((long)b * MAXK + kk) * DIM + c4 * 4)
            : make_float4(0.f, 0.f, 0.f, 0.f);
        ushort4 h; ushort* hp = (ushort*)&h;
        hp[0] = f2b_rn(v.x); hp[1] = f2b_rn(v.y);
        hp[2] = f2b_rn(v.z); hp[3] = f2b_rn(v.w);
        *(ushort4*)&Ch[row * 136 + c4 * 4] = h;
    }
    __syncthreads();

    // per-cluster inv-norms from staged C (quad-split over d, shuffle-combine)
    {
        int c = w * 16 + m16;
        float ssv = 0.f;
        #pragma unroll
        for (int j = 0; j < 16; ++j) {
            unsigned int u = *(const unsigned int*)&Ch[c * 136 + quad * 32 + j * 2];
            float x0 = b2f((ushort)u), x1 = b2f((ushort)(u >> 16));
            ssv += x0 * x0 + x1 * x1;
        }
        ssv += __shfl_xor(ssv, 16);
        ssv += __shfl_xor(ssv, 32);
        if (quad == 0) cn[c] = (ssv > 1e-24f) ? rsqrtf(ssv) : 0.f;
    }
    __syncthreads();

    // MFMA: wave w -> q rows [w*16, w*16+16), all 64 clusters (4 ct tiles)
    f32x4 acc[4];
    #pragma unroll
    for (int j = 0; j < 4; ++j) acc[j] = (f32x4){0.f, 0.f, 0.f, 0.f};

    #pragma unroll
    for (int kc = 0; kc < 4; ++kc) {
        short8 qh = *(const short8*)&Qh[(w * 16 + m16) * 136 + kc * 32 + quad * 8];
        short8 ql = *(const short8*)&Ql[(w * 16 + m16) * 136 + kc * 32 + quad * 8];
        #pragma unroll
        for (int ct = 0; ct < 4; ++ct) {
            short8 cf = *(const short8*)&Ch[(ct * 16 + m16) * 136 + kc * 32 + quad * 8];
            acc[ct] = __builtin_amdgcn_mfma_f32_16x16x32_bf16(qh, cf, acc[ct], 0, 0, 0);
            acc[ct] = __builtin_amdgcn_mfma_f32_16x16x32_bf16(ql, cf, acc[ct], 0, 0, 0);
        }
    }

    int kb = kvals[b];
    #pragma unroll
    for (int r = 0; r < 4; ++r) {
        float mx = -1e4f;
        #pragma unroll
        for (int ct = 0; ct < 4; ++ct) {
            int cl = chunk * 64 + ct * 16 + m16;
            float sim = acc[ct][r] * cn[ct * 16 + m16];
            mx = fmaxf(mx, (cl < kb) ? sim : -1e4f);
        }
        mx = fmaxf(mx, __shfl_xor(mx, 1));
        mx = fmaxf(mx, __shfl_xor(mx, 2));
        mx = fmaxf(mx, __shfl_xor(mx, 4));
        mx = fmaxf(mx, __shfl_xor(mx, 8));
        if (m16 == 0)
            pmax[((long)b * SCH + chunk) * 64 + w * 16 + quad * 4 + r] = mx;
    }
}

// ---------------------------------------------------------------------------
// Final: per batch, max over chunks, *q_mask, sum over rows -> out[b]
__global__ __launch_bounds__(64) void final_kernel(
    const float* __restrict__ pmax,
    const int*   __restrict__ q_mask,
    float*       __restrict__ out)
{
    int b = blockIdx.x, r = threadIdx.x;
    float m = -3e38f;
    #pragma unroll
    for (int c = 0; c < SCH; ++c)
        m = fmaxf(m, pmax[((long)b * SCH + c) * 64 + r]);
    m *= (float)q_mask[b * LQ + r];
    #pragma unroll
    for (int sh = 1; sh < 64; sh <<= 1) m += __shfl_xor(m, sh);
    if (r == 0) out[b] = m;
}

// ---------------------------------------------------------------------------
extern "C" void kernel_launch(void* const* d_in, const int* in_sizes, int n_in,
                              void* d_out, int out_size, void* d_ws, size_t ws_size,
                              hipStream_t stream) {
    const float* q_hidden = (const float*)d_in[0];
    const float* d_hidden = (const float*)d_in[1];
    const float* W        = (const float*)d_in[2];
    const float* bias     = (const float*)d_in[3];
    const int*   q_mask   = (const int*)d_in[4];
    const int*   d_mask   = (const int*)d_in[5];
    const int*   labels   = (const int*)d_in[6];
    const int*   pf       = (const int*)d_in[7];

    float* ws     = (float*)d_ws;
    float* q_repr = ws;                                   // 131,072 f
    float* sums   = q_repr + (long)BB * LQ * DIM;         // 1,050,624 f
    float* pmaxb  = sums + (long)BB * MAXK * DIM;         // 16*9*64 = 9,216 f
    int*   kvals  = (int*)(pmaxb + BB * SCH * 64);        // 16
    ushort* Wt    = (ushort*)(kvals + 16);                // 131,072 bf16

    hipMemsetAsync(sums, 0, (size_t)BB * MAXK * DIM * sizeof(float), stream);

    prep_kb_kernel<<<512 + BB, 256, 0, stream>>>(W, d_mask, pf, Wt, kvals);
    encode_kernel<<<DGRID + QGRID, 256, 0, stream>>>(d_hidden, q_hidden, Wt, bias,
                                                     d_mask, q_mask, labels, kvals,
                                                     sums, q_repr);
    simmax_kernel<<<BB * SCH, 256, 0, stream>>>(q_repr, sums, kvals, pmaxb);
    final_kernel<<<BB, 64, 0, stream>>>(pmaxb, q_mask, (float*)d_out);
}